// Round 5
// baseline (306.407 us; speedup 1.0000x reference)
//
#include <hip/hip_runtime.h>

#define N_NODES 40000
#define N_EDGES 640000
#define HID 128
#define NHEAD 8

typedef __attribute__((ext_vector_type(8))) short short8;
typedef __attribute__((ext_vector_type(4))) short short4v;
typedef __attribute__((ext_vector_type(4))) float f32x4;

// ---------------- workspace layout (bytes) ----------------
static constexpr size_t OFF_QKV  = 0;          // [40000][384] bf16 = 30,720,000
static constexpr size_t OFF_AOB  = 30720000;   // [40000][128] bf16 = 10,240,000
static constexpr size_t OFF_XB   = 40960000;   // [40000][128] bf16
static constexpr size_t OFF_TB   = 51200000;   // [40000][256] bf16 = 20,480,000
static constexpr size_t OFF_HB   = 71680000;   // [40000][128] bf16 = 10,240,000
static constexpr size_t OFF_WQKV = 81920000;   // [384][128] bf16
static constexpr size_t OFF_WTO  = 82018304;   // [128][128] bf16
static constexpr size_t OFF_WT1  = 82051072;   // [256][128] bf16
static constexpr size_t OFF_WT2  = 82116608;   // [128][256] bf16
static constexpr size_t OFF_BQKV = 82182144;   // 384 f32
static constexpr size_t OFF_DEG  = 82240000;   // N*4
static constexpr size_t OFF_OFFS = 82400000;
static constexpr size_t OFF_CUR  = 82560000;
static constexpr size_t OFF_COLW = 82720000;   // E*4 = 2,560,000
static constexpr size_t OFF_BSUM = 85280000;   // 157*4
static constexpr size_t OFF_ST   = 85281024;   // 512 f32 (st1, st2)
// total ~85.3 MB

__device__ inline unsigned short f2b(float f) {
    unsigned x = __float_as_uint(f);
    unsigned r = x + 0x7fffu + ((x >> 16) & 1u);   // RNE
    return (unsigned short)(r >> 16);
}
__device__ inline float b2f(unsigned short u) {
    return __uint_as_float(((unsigned)u) << 16);
}

// ---------------- h -> bf16 ----------------
__global__ void h2b_kernel(const float* __restrict__ h, unsigned short* __restrict__ hb)
{
    const int i = (blockIdx.x * 256 + threadIdx.x) * 8;
    float4 f0 = *(const float4*)(h + i);
    float4 f1 = *(const float4*)(h + i + 4);
    short8 w;
    w[0] = (short)f2b(f0.x); w[1] = (short)f2b(f0.y);
    w[2] = (short)f2b(f0.z); w[3] = (short)f2b(f0.w);
    w[4] = (short)f2b(f1.x); w[5] = (short)f2b(f1.y);
    w[6] = (short)f2b(f1.z); w[7] = (short)f2b(f1.w);
    *(short8*)(hb + i) = w;
}

// ---------------- weight pre-transpose + bf16 convert ----------------
__global__ void wt_kernel(const float* __restrict__ Wq, const float* __restrict__ Wk,
                          const float* __restrict__ Wv, const float* __restrict__ Wo,
                          const float* __restrict__ W1, const float* __restrict__ W2,
                          const float* __restrict__ bq, const float* __restrict__ bk,
                          const float* __restrict__ bv,
                          unsigned short* __restrict__ WTqkv, unsigned short* __restrict__ WTo,
                          unsigned short* __restrict__ WT1, unsigned short* __restrict__ WT2,
                          float* __restrict__ bqkv)
{
    int i = blockIdx.x * 256 + threadIdx.x;   // 0..131071
    if (i < 16384) {
        int k = i >> 7, n = i & 127;
        WTqkv[n * 128 + k] = f2b(0.25f * Wq[i]);
    } else if (i < 32768) {
        int j = i - 16384; int k = j >> 7, n = j & 127;
        WTqkv[(128 + n) * 128 + k] = f2b(Wk[j]);
    } else if (i < 49152) {
        int j = i - 32768; int k = j >> 7, n = j & 127;
        WTqkv[(256 + n) * 128 + k] = f2b(Wv[j]);
    } else if (i < 65536) {
        int j = i - 49152; int k = j >> 7, n = j & 127;
        WTo[n * 128 + k] = f2b(Wo[j]);
    } else if (i < 98304) {
        int j = i - 65536; int k = j >> 8, n = j & 255;
        WT1[n * 128 + k] = f2b(W1[j]);
    } else {
        int j = i - 98304; int k = j >> 7, n = j & 127;
        WT2[n * 256 + k] = f2b(W2[j]);
    }
    if (blockIdx.x == 0 && threadIdx.x < 384) {
        int c = threadIdx.x;
        float v = (c < 128) ? 0.25f * bq[c] : (c < 256) ? bk[c - 128] : bv[c - 256];
        bqkv[c] = v;
    }
}

// ---------------- bf16 MFMA GEMM, BM=128 x BN=128, BK=64 ----------------
// C[M][NTOT] = act((A[M][K] @ WT^T) + bias [+ res]); A bf16 [M][K], WT [NTOT][K].
// 256 thr = 4 waves in 2x2; wave (wr,wc) owns 64x64 quadrant, acc[4][4] 16x16 frags.
// Rows clamped at stage, writes/stats gated on r < N_NODES.
template<typename TC, typename TR, int K, int NTOT, bool ACT, bool STATS>
__global__ __launch_bounds__(256) void mm_kernel(
    const unsigned short* __restrict__ A, const unsigned short* __restrict__ WT,
    const float* __restrict__ bias, const TR* __restrict__ res,
    TC* __restrict__ C, float* __restrict__ st)
{
    __shared__ unsigned short As[128][72];
    __shared__ unsigned short Bs[128][72];
    const int t = threadIdx.x;
    const int lane = t & 63, wave = t >> 6;
    const int wr = wave >> 1, wc = wave & 1;
    const int row0 = blockIdx.x * 128;
    const int colOff = blockIdx.y * 128;

    f32x4 acc[4][4];
#pragma unroll
    for (int i = 0; i < 4; ++i)
#pragma unroll
        for (int j = 0; j < 4; ++j) acc[i][j] = (f32x4){0.f, 0.f, 0.f, 0.f};

    const int r0 = t >> 1;                       // 0..127 (tile row / weight row)
    const int ar = min(row0 + r0, N_NODES - 1);  // clamped source row
    const int kc = (t & 1) * 32;

    for (int k0 = 0; k0 < K; k0 += 64) {
        const unsigned short* ap = A + (size_t)ar * K + k0 + kc;
        short8 av0 = *(const short8*)(ap);
        short8 av1 = *(const short8*)(ap + 8);
        short8 av2 = *(const short8*)(ap + 16);
        short8 av3 = *(const short8*)(ap + 24);
        const unsigned short* wp = WT + (size_t)(colOff + r0) * K + k0 + kc;
        short8 bv0 = *(const short8*)(wp);
        short8 bv1 = *(const short8*)(wp + 8);
        short8 bv2 = *(const short8*)(wp + 16);
        short8 bv3 = *(const short8*)(wp + 24);
        __syncthreads();   // previous iteration's reads done
        *(short8*)&As[r0][kc]      = av0;
        *(short8*)&As[r0][kc + 8]  = av1;
        *(short8*)&As[r0][kc + 16] = av2;
        *(short8*)&As[r0][kc + 24] = av3;
        *(short8*)&Bs[r0][kc]      = bv0;
        *(short8*)&Bs[r0][kc + 8]  = bv1;
        *(short8*)&Bs[r0][kc + 16] = bv2;
        *(short8*)&Bs[r0][kc + 24] = bv3;
        __syncthreads();

#pragma unroll
        for (int ks = 0; ks < 2; ++ks) {
            const int kf = ks * 32 + (lane >> 4) * 8;
            short8 af[4], bf_[4];
#pragma unroll
            for (int mi = 0; mi < 4; ++mi)
                af[mi] = *(short8*)&As[wr * 64 + mi * 16 + (lane & 15)][kf];
#pragma unroll
            for (int ni = 0; ni < 4; ++ni)
                bf_[ni] = *(short8*)&Bs[wc * 64 + ni * 16 + (lane & 15)][kf];
#pragma unroll
            for (int mi = 0; mi < 4; ++mi)
#pragma unroll
                for (int ni = 0; ni < 4; ++ni)
                    acc[mi][ni] = __builtin_amdgcn_mfma_f32_16x16x32_bf16(
                        af[mi], bf_[ni], acc[mi][ni], 0, 0, 0);
        }
    }

    float csum[4] = {0.f, 0.f, 0.f, 0.f}, csq[4] = {0.f, 0.f, 0.f, 0.f};
#pragma unroll
    for (int mi = 0; mi < 4; ++mi) {
#pragma unroll
        for (int ni = 0; ni < 4; ++ni) {
            const int c = colOff + wc * 64 + ni * 16 + (lane & 15);
            const float bv_ = bias[c];
#pragma unroll
            for (int reg = 0; reg < 4; ++reg) {
                const int r = row0 + wr * 64 + mi * 16 + (lane >> 4) * 4 + reg;
                if (r < N_NODES) {
                    float val = acc[mi][ni][reg] + bv_;
                    if constexpr (!__is_same(TR, void)) {
                        if constexpr (sizeof(TR) == 4)
                            val += ((const float*)res)[(size_t)r * 128 + c];
                        else
                            val += b2f(((const unsigned short*)res)[(size_t)r * 128 + c]);
                    }
                    if constexpr (ACT)
                        val = 0.5f * val * (1.0f + erff(val * 0.70710678118654752f));
                    if constexpr (STATS) {
                        csum[ni] += val;
                        csq[ni]  += val * val;
                    }
                    if constexpr (sizeof(TC) == 4)
                        ((float*)C)[(size_t)r * NTOT + c] = val;
                    else
                        ((unsigned short*)C)[(size_t)r * NTOT + c] = f2b(val);
                }
            }
        }
    }

    if constexpr (STATS) {   // NTOT==128 only
#pragma unroll
        for (int ni = 0; ni < 4; ++ni) {
            float s = csum[ni], qq = csq[ni];
            s  += __shfl_xor(s, 16, 64);  s  += __shfl_xor(s, 32, 64);
            qq += __shfl_xor(qq, 16, 64); qq += __shfl_xor(qq, 32, 64);
            if (lane < 16) {
                const int c = wc * 64 + ni * 16 + lane;
                atomicAdd(st + c, s);
                atomicAdd(st + 128 + c, qq);
            }
        }
    }
}

// ---------------- CSR build ----------------
__global__ void count_kernel(const int* __restrict__ row, int* __restrict__ deg)
{
    int e = blockIdx.x * 256 + threadIdx.x;
    if (e < N_EDGES) atomicAdd(deg + row[e], 1);
}

__global__ __launch_bounds__(256) void bsum_kernel(const int* __restrict__ deg,
                                                   int* __restrict__ bsum)
{
    __shared__ int ws[4];
    int idx = blockIdx.x * 256 + threadIdx.x;
    int v = (idx < N_NODES) ? deg[idx] : 0;
#pragma unroll
    for (int ofs = 1; ofs < 64; ofs <<= 1) v += __shfl_xor(v, ofs, 64);
    if ((threadIdx.x & 63) == 0) ws[threadIdx.x >> 6] = v;
    __syncthreads();
    if (threadIdx.x == 0) bsum[blockIdx.x] = ws[0] + ws[1] + ws[2] + ws[3];
}

__global__ __launch_bounds__(256) void scan2_kernel(const int* __restrict__ deg,
                                                    const int* __restrict__ bsum,
                                                    int* __restrict__ offs,
                                                    int* __restrict__ cur)
{
    __shared__ int wsum[4];
    __shared__ int base_s;
    const int t = threadIdx.x, lane = t & 63, w = t >> 6;

    int p = 0;
    for (int i = t; i < blockIdx.x; i += 256) p += bsum[i];
#pragma unroll
    for (int ofs = 1; ofs < 64; ofs <<= 1) p += __shfl_xor(p, ofs, 64);
    if (lane == 0) wsum[w] = p;
    __syncthreads();
    if (t == 0) base_s = wsum[0] + wsum[1] + wsum[2] + wsum[3];
    __syncthreads();

    int idx = blockIdx.x * 256 + t;
    int v = (idx < N_NODES) ? deg[idx] : 0;
    int x = v;
#pragma unroll
    for (int d = 1; d < 64; d <<= 1) {
        int y = __shfl_up(x, d, 64);
        if (lane >= d) x += y;
    }
    __syncthreads();
    if (lane == 63) wsum[w] = x;
    __syncthreads();
    int pre = base_s;
    for (int i = 0; i < w; ++i) pre += wsum[i];
    int excl = pre + x - v;
    if (idx < N_NODES) { offs[idx] = excl; cur[idx] = excl; }
}

// scatter writes source-node BYTE-ish offset (col*384) directly
__global__ void scatter_kernel(const int* __restrict__ row, const int* __restrict__ col,
                               int* __restrict__ cursor, int* __restrict__ colw)
{
    int e = blockIdx.x * 256 + threadIdx.x;
    if (e < N_EDGES) {
        int pos = atomicAdd(cursor + row[e], 1);
        colw[pos] = col[e] * 384;
    }
}

// ---------------- fused attention (bf16), one wave per node ----------------
// qkv: [node][384] bf16 (q 0..127 pre-scaled, k 128..255, v 256..383).
// Scores ~N(0,0.33^2) -> exp() w/o max-subtraction safe; /z normalizes.
// 16-edge batches: 32 independent gathers in flight before compute.
__global__ __launch_bounds__(256) void attn_kernel(
    const unsigned short* __restrict__ qkv, const int* __restrict__ colw,
    const int* __restrict__ offs, const int* __restrict__ deg,
    unsigned short* __restrict__ aob)
{
    const int node = blockIdx.x * 4 + (threadIdx.x >> 6);
    const int lane = threadIdx.x & 63;
    const int c0 = 2 * lane;
    const int start = offs[node];
    const int d = deg[node];

    unsigned qu = *(const unsigned*)(qkv + (size_t)node * 384 + c0);
    float q0 = __uint_as_float(qu << 16);
    float q1 = __uint_as_float(qu & 0xffff0000u);
    float z0 = 0.f, z1 = 0.f, o0 = 0.f, o1 = 0.f;

#define ATTN_EDGE(KU, VU)                                              \
    {                                                                  \
        float p0 = q0 * __uint_as_float((KU) << 16);                   \
        float p1 = q1 * __uint_as_float((KU) & 0xffff0000u);           \
        _Pragma("unroll")                                              \
        for (int ofs = 4; ofs < 64; ofs <<= 1) {                       \
            p0 += __shfl_xor(p0, ofs, 64);                             \
            p1 += __shfl_xor(p1, ofs, 64);                             \
        }                                                              \
        float e0 = __expf(p0), e1 = __expf(p1);                        \
        z0 += e0; z1 += e1;                                            \
        o0 = fmaf(e0, __uint_as_float((VU) << 16), o0);                \
        o1 = fmaf(e1, __uint_as_float((VU) & 0xffff0000u), o1);        \
    }

    for (int base = 0; base < d; base += 64) {
        const int nrem = min(64, d - base);
        int cls = 0;
        if (lane < nrem) cls = colw[start + base + lane];   // pre-scaled *384
        int j = 0;
        for (; j + 16 <= nrem; j += 16) {
            unsigned ku[16], vu[16];
#pragma unroll
            for (int u = 0; u < 16; ++u) {
                int cs = __shfl(cls, j + u, 64);
                const unsigned short* rp = qkv + cs;
                ku[u] = *(const unsigned*)(rp + 128 + c0);
                vu[u] = *(const unsigned*)(rp + 256 + c0);
            }
#pragma unroll
            for (int u = 0; u < 16; ++u) ATTN_EDGE(ku[u], vu[u]);
        }
        for (; j + 8 <= nrem; j += 8) {
            unsigned ku[8], vu[8];
#pragma unroll
            for (int u = 0; u < 8; ++u) {
                int cs = __shfl(cls, j + u, 64);
                const unsigned short* rp = qkv + cs;
                ku[u] = *(const unsigned*)(rp + 128 + c0);
                vu[u] = *(const unsigned*)(rp + 256 + c0);
            }
#pragma unroll
            for (int u = 0; u < 8; ++u) ATTN_EDGE(ku[u], vu[u]);
        }
        for (; j < nrem; ++j) {
            int cs = __shfl(cls, j, 64);
            const unsigned short* rp = qkv + cs;
            unsigned ku = *(const unsigned*)(rp + 128 + c0);
            unsigned vu = *(const unsigned*)(rp + 256 + c0);
            ATTN_EDGE(ku, vu);
        }
    }
    float r0 = (d > 0) ? o0 / z0 : 0.f;
    float r1 = (d > 0) ? o1 / z1 : 0.f;
    *(unsigned*)(aob + (size_t)node * HID + c0) =
        (unsigned)f2b(r0) | ((unsigned)f2b(r1) << 16);
}

// ---------------- BN apply (+ optional exact GELU), float4 vectorized ----------------
template<typename TO, bool ACT>
__global__ void bn_kernel(const float* __restrict__ x, const float* __restrict__ st,
                          const float* __restrict__ g, const float* __restrict__ b,
                          TO* __restrict__ out)
{
    const int i = (blockIdx.x * 256 + threadIdx.x) * 4;
    const int c = i & (HID - 1);
    float4 xv = *(const float4*)(x + i);
    float v[4] = {xv.x, xv.y, xv.z, xv.w};
#pragma unroll
    for (int u = 0; u < 4; ++u) {
        const int cc = c + u;
        float mu  = st[cc] * (1.0f / N_NODES);
        float var = st[HID + cc] * (1.0f / N_NODES) - mu * mu;
        float val = (v[u] - mu) * rsqrtf(var + 1e-5f) * g[cc] + b[cc];
        if constexpr (ACT) val = 0.5f * val * (1.0f + erff(val * 0.70710678118654752f));
        v[u] = val;
    }
    if constexpr (sizeof(TO) == 4) {
        *(float4*)((float*)out + i) = (float4){v[0], v[1], v[2], v[3]};
    } else {
        short4v w;
        w[0] = (short)f2b(v[0]); w[1] = (short)f2b(v[1]);
        w[2] = (short)f2b(v[2]); w[3] = (short)f2b(v[3]);
        *(short4v*)((unsigned short*)out + i) = w;
    }
}

extern "C" void kernel_launch(void* const* d_in, const int* in_sizes, int n_in,
                              void* d_out, int out_size, void* d_ws, size_t ws_size,
                              hipStream_t stream)
{
    const float* h   = (const float*)d_in[0];
    const int*   row = (const int*)d_in[1];
    const int*   col = (const int*)d_in[2];
    const float* Wq  = (const float*)d_in[3];
    const float* bq  = (const float*)d_in[4];
    const float* Wk  = (const float*)d_in[5];
    const float* bk  = (const float*)d_in[6];
    const float* Wv  = (const float*)d_in[7];
    const float* bv  = (const float*)d_in[8];
    const float* Wo  = (const float*)d_in[9];
    const float* bo  = (const float*)d_in[10];
    const float* W1  = (const float*)d_in[11];
    const float* bf1 = (const float*)d_in[12];
    const float* W2  = (const float*)d_in[13];
    const float* bf2 = (const float*)d_in[14];
    const float* g1  = (const float*)d_in[15];
    const float* b1  = (const float*)d_in[16];
    const float* g2  = (const float*)d_in[17];
    const float* b2  = (const float*)d_in[18];

    float* out = (float*)d_out;
    char*  ws  = (char*)d_ws;

    unsigned short* qkv  = (unsigned short*)(ws + OFF_QKV);
    unsigned short* aob  = (unsigned short*)(ws + OFF_AOB);
    unsigned short* xb   = (unsigned short*)(ws + OFF_XB);
    unsigned short* tb   = (unsigned short*)(ws + OFF_TB);
    unsigned short* hb   = (unsigned short*)(ws + OFF_HB);
    unsigned short* WTqkv= (unsigned short*)(ws + OFF_WQKV);
    unsigned short* WTo  = (unsigned short*)(ws + OFF_WTO);
    unsigned short* WT1  = (unsigned short*)(ws + OFF_WT1);
    unsigned short* WT2  = (unsigned short*)(ws + OFF_WT2);
    float* bqkv = (float*)(ws + OFF_BQKV);
    int*   deg  = (int*)(ws + OFF_DEG);
    int*   offs = (int*)(ws + OFF_OFFS);
    int*   cur  = (int*)(ws + OFF_CUR);
    int*   colw = (int*)(ws + OFF_COLW);
    int*   bsum = (int*)(ws + OFF_BSUM);
    float* st1  = (float*)(ws + OFF_ST);
    float* st2  = st1 + 256;

    hipMemsetAsync(ws + OFF_DEG, 0, (size_t)N_NODES * 4, stream);
    hipMemsetAsync(ws + OFF_ST,  0, 2048, stream);

    dim3 blk(256);
    const int nScanBlocks = (N_NODES + 255) / 256;  // 157
    const int nRowTiles   = (N_NODES + 127) / 128;  // 313

    wt_kernel<<<dim3(512), blk, 0, stream>>>(Wq, Wk, Wv, Wo, W1, W2, bq, bk, bv,
                                             WTqkv, WTo, WT1, WT2, bqkv);
    h2b_kernel<<<dim3(2500), blk, 0, stream>>>(h, hb);

    // fused QKV projection: [40000][384] bf16
    mm_kernel<unsigned short, void, 128, 384, false, false>
        <<<dim3(nRowTiles, 3), blk, 0, stream>>>(hb, WTqkv, bqkv, nullptr, qkv, nullptr);

    // CSR build
    count_kernel<<<dim3(N_EDGES / 256), blk, 0, stream>>>(row, deg);
    bsum_kernel<<<dim3(nScanBlocks), blk, 0, stream>>>(deg, bsum);
    scan2_kernel<<<dim3(nScanBlocks), blk, 0, stream>>>(deg, bsum, offs, cur);
    scatter_kernel<<<dim3(N_EDGES / 256), blk, 0, stream>>>(row, col, cur, colw);

    // fused attention
    attn_kernel<<<dim3(N_NODES / 4), blk, 0, stream>>>(qkv, colw, offs, deg, aob);

    // output projection + residual(h) -> x0 (f32, d_out), fused BN1 stats
    mm_kernel<float, float, 128, 128, false, true>
        <<<dim3(nRowTiles, 1), blk, 0, stream>>>(aob, WTo, bo, h, out, st1);

    // BN1 + GELU -> x (bf16)
    bn_kernel<unsigned short, true>
        <<<dim3(N_NODES * HID / 1024), blk, 0, stream>>>(out, st1, g1, b1, xb);

    // FFN1: x @ W1 + b -> GELU -> t (bf16)
    mm_kernel<unsigned short, void, 128, 256, true, false>
        <<<dim3(nRowTiles, 2), blk, 0, stream>>>(xb, WT1, bf1, nullptr, tb, nullptr);

    // FFN2: t @ W2 + b + x -> y0 (f32, d_out), fused BN2 stats
    mm_kernel<float, unsigned short, 256, 128, false, true>
        <<<dim3(nRowTiles, 1), blk, 0, stream>>>(tb, WT2, bf2, xb, out, st2);

    // BN2 -> final output (in place on d_out)
    bn_kernel<float, false>
        <<<dim3(N_NODES * HID / 1024), blk, 0, stream>>>(out, st2, g2, b2, out);
}

// Round 6
// 258.303 us; speedup vs baseline: 1.1862x; 1.1862x over previous
//
#include <hip/hip_runtime.h>

#define N_NODES 40000
#define N_EDGES 640000
#define HID 128
#define NHEAD 8

typedef __attribute__((ext_vector_type(8))) short short8;
typedef __attribute__((ext_vector_type(4))) short short4v;
typedef __attribute__((ext_vector_type(4))) float f32x4;

// ---------------- workspace layout (bytes) ----------------
static constexpr size_t OFF_QB   = 0;          // [40000][128] bf16 = 10,240,000 (q, pre-scaled)
static constexpr size_t OFF_KV8  = 10240000;   // [40000][256B] fp8 kv packed = 10,240,000
static constexpr size_t OFF_AOB  = 20480000;   // [40000][128] bf16
static constexpr size_t OFF_XB   = 30720000;   // [40000][128] bf16
static constexpr size_t OFF_TB   = 40960000;   // [40000][256] bf16 = 20,480,000
static constexpr size_t OFF_HB   = 61440000;   // [40000][128] bf16
static constexpr size_t OFF_WQKV = 71680000;   // [384][128] bf16
static constexpr size_t OFF_WTO  = 71778304;   // [128][128] bf16
static constexpr size_t OFF_WT1  = 71811072;   // [256][128] bf16
static constexpr size_t OFF_WT2  = 71876608;   // [128][256] bf16
static constexpr size_t OFF_BQKV = 71942144;   // 384 f32
static constexpr size_t OFF_DEG  = 72000000;   // N*4
static constexpr size_t OFF_OFFS = 72160000;
static constexpr size_t OFF_CUR  = 72320000;
static constexpr size_t OFF_COLW = 72480000;   // E*4
static constexpr size_t OFF_BSUM = 75040000;   // 157*4
static constexpr size_t OFF_ST   = 75041024;   // 512 f32
// total ~75.05 MB

__device__ inline unsigned short f2b(float f) {
    unsigned x = __float_as_uint(f);
    unsigned r = x + 0x7fffu + ((x >> 16) & 1u);   // RNE
    return (unsigned short)(r >> 16);
}
__device__ inline float b2f(unsigned short u) {
    return __uint_as_float(((unsigned)u) << 16);
}
__device__ inline unsigned char f2fp8(float f) {
    return (unsigned char)(__builtin_amdgcn_cvt_pk_fp8_f32(f, f, 0, false) & 0xff);
}

// ---------------- h -> bf16 ----------------
__global__ void h2b_kernel(const float* __restrict__ h, unsigned short* __restrict__ hb)
{
    const int i = (blockIdx.x * 256 + threadIdx.x) * 8;
    float4 f0 = *(const float4*)(h + i);
    float4 f1 = *(const float4*)(h + i + 4);
    short8 w;
    w[0] = (short)f2b(f0.x); w[1] = (short)f2b(f0.y);
    w[2] = (short)f2b(f0.z); w[3] = (short)f2b(f0.w);
    w[4] = (short)f2b(f1.x); w[5] = (short)f2b(f1.y);
    w[6] = (short)f2b(f1.z); w[7] = (short)f2b(f1.w);
    *(short8*)(hb + i) = w;
}

// ---------------- weight pre-transpose + bf16 convert ----------------
__global__ void wt_kernel(const float* __restrict__ Wq, const float* __restrict__ Wk,
                          const float* __restrict__ Wv, const float* __restrict__ Wo,
                          const float* __restrict__ W1, const float* __restrict__ W2,
                          const float* __restrict__ bq, const float* __restrict__ bk,
                          const float* __restrict__ bv,
                          unsigned short* __restrict__ WTqkv, unsigned short* __restrict__ WTo,
                          unsigned short* __restrict__ WT1, unsigned short* __restrict__ WT2,
                          float* __restrict__ bqkv)
{
    int i = blockIdx.x * 256 + threadIdx.x;   // 0..131071
    if (i < 16384) {
        int k = i >> 7, n = i & 127;
        WTqkv[n * 128 + k] = f2b(0.25f * Wq[i]);
    } else if (i < 32768) {
        int j = i - 16384; int k = j >> 7, n = j & 127;
        WTqkv[(128 + n) * 128 + k] = f2b(Wk[j]);
    } else if (i < 49152) {
        int j = i - 32768; int k = j >> 7, n = j & 127;
        WTqkv[(256 + n) * 128 + k] = f2b(Wv[j]);
    } else if (i < 65536) {
        int j = i - 49152; int k = j >> 7, n = j & 127;
        WTo[n * 128 + k] = f2b(Wo[j]);
    } else if (i < 98304) {
        int j = i - 65536; int k = j >> 8, n = j & 255;
        WT1[n * 128 + k] = f2b(W1[j]);
    } else {
        int j = i - 98304; int k = j >> 7, n = j & 127;
        WT2[n * 256 + k] = f2b(W2[j]);
    }
    if (blockIdx.x == 0 && threadIdx.x < 384) {
        int c = threadIdx.x;
        float v = (c < 128) ? 0.25f * bq[c] : (c < 256) ? bk[c - 128] : bv[c - 256];
        bqkv[c] = v;
    }
}

// ---------------- bf16 MFMA GEMM (BM=64, BN=128, BK=128) ----------------
// C = act((A @ WT^T) + bias [+ res]); A bf16 [M][K], WT [NTOT][K] bf16.
// 256 thr = 4 waves; wave owns 32 cols, acc[4][2] of 16x16 frags.
// QKVMODE: colOff==0 -> bf16 q to C[r*128+c]; else fp8 byte into kv8 packed rows.
template<typename TC, typename TR, int K, int NTOT, bool ACT, bool STATS, bool QKVMODE>
__global__ __launch_bounds__(256) void mm_kernel(
    const unsigned short* __restrict__ A, const unsigned short* __restrict__ WT,
    const float* __restrict__ bias, const TR* __restrict__ res,
    TC* __restrict__ C, unsigned char* __restrict__ kv8, float* __restrict__ st)
{
    __shared__ unsigned short As[64][136];
    __shared__ unsigned short Bs[128][136];
    const int t = threadIdx.x;
    const int lane = t & 63, wave = t >> 6;
    const int row0 = blockIdx.x * 64;
    const int colOff = blockIdx.y * 128;

    f32x4 acc[4][2];
#pragma unroll
    for (int i = 0; i < 4; ++i)
#pragma unroll
        for (int j = 0; j < 2; ++j) acc[i][j] = (f32x4){0.f, 0.f, 0.f, 0.f};

    for (int k0 = 0; k0 < K; k0 += 128) {
        {
            const int r = t >> 2, kc = (t & 3) * 32;
            const unsigned short* ap = A + (size_t)(row0 + r) * K + k0 + kc;
#pragma unroll
            for (int i = 0; i < 4; ++i)
                *(short8*)&As[r][kc + 8 * i] = *(const short8*)(ap + 8 * i);
        }
        {
            const int n = t >> 1, kc = (t & 1) * 64;
            const unsigned short* wp = WT + (size_t)(colOff + n) * K + k0 + kc;
#pragma unroll
            for (int i = 0; i < 8; ++i)
                *(short8*)&Bs[n][kc + 8 * i] = *(const short8*)(wp + 8 * i);
        }
        __syncthreads();

#pragma unroll
        for (int ks = 0; ks < 4; ++ks) {
            const int kf = ks * 32 + (lane >> 4) * 8;
            short8 af[4], bf_[2];
#pragma unroll
            for (int mi = 0; mi < 4; ++mi)
                af[mi] = *(short8*)&As[mi * 16 + (lane & 15)][kf];
#pragma unroll
            for (int ni = 0; ni < 2; ++ni)
                bf_[ni] = *(short8*)&Bs[wave * 32 + ni * 16 + (lane & 15)][kf];
#pragma unroll
            for (int mi = 0; mi < 4; ++mi)
#pragma unroll
                for (int ni = 0; ni < 2; ++ni)
                    acc[mi][ni] = __builtin_amdgcn_mfma_f32_16x16x32_bf16(
                        af[mi], bf_[ni], acc[mi][ni], 0, 0, 0);
        }
        __syncthreads();
    }

    float csum[2] = {0.f, 0.f}, csq[2] = {0.f, 0.f};
#pragma unroll
    for (int mi = 0; mi < 4; ++mi) {
#pragma unroll
        for (int ni = 0; ni < 2; ++ni) {
            const int lc = wave * 32 + ni * 16 + (lane & 15);   // local col 0..127
            const int c = colOff + lc;
            const float bv_ = bias[c];
#pragma unroll
            for (int reg = 0; reg < 4; ++reg) {
                const int r = row0 + mi * 16 + (lane >> 4) * 4 + reg;
                float val = acc[mi][ni][reg] + bv_;
                if constexpr (!__is_same(TR, void)) {
                    if constexpr (sizeof(TR) == 4)
                        val += ((const float*)res)[(size_t)r * 128 + c];
                    else
                        val += b2f(((const unsigned short*)res)[(size_t)r * 128 + c]);
                }
                if constexpr (ACT)
                    val = 0.5f * val * (1.0f + erff(val * 0.70710678118654752f));
                if constexpr (STATS) {
                    csum[ni] += val;
                    csq[ni]  += val * val;
                }
                if constexpr (QKVMODE) {
                    if (colOff == 0) {
                        ((unsigned short*)C)[(size_t)r * 128 + lc] = f2b(val);
                    } else {
                        // packed kv8 row: dword l = {k[2l],k[2l+1],v[2l],v[2l+1]}
                        const int idx = (lc >> 1) * 4 + (lc & 1) + ((colOff == 256) ? 2 : 0);
                        kv8[(size_t)r * 256 + idx] = f2fp8(val);
                    }
                } else {
                    if constexpr (sizeof(TC) == 4)
                        ((float*)C)[(size_t)r * NTOT + c] = val;
                    else
                        ((unsigned short*)C)[(size_t)r * NTOT + c] = f2b(val);
                }
            }
        }
    }

    if constexpr (STATS) {   // NTOT==128 only
#pragma unroll
        for (int ni = 0; ni < 2; ++ni) {
            float s = csum[ni], qq = csq[ni];
            s  += __shfl_xor(s, 16, 64);  s  += __shfl_xor(s, 32, 64);
            qq += __shfl_xor(qq, 16, 64); qq += __shfl_xor(qq, 32, 64);
            if (lane < 16) {
                const int c = wave * 32 + ni * 16 + lane;
                atomicAdd(st + c, s);
                atomicAdd(st + 128 + c, qq);
            }
        }
    }
}

// ---------------- CSR build ----------------
__global__ void count_kernel(const int* __restrict__ row, int* __restrict__ deg)
{
    int e = blockIdx.x * 256 + threadIdx.x;
    if (e < N_EDGES) atomicAdd(deg + row[e], 1);
}

__global__ __launch_bounds__(256) void bsum_kernel(const int* __restrict__ deg,
                                                   int* __restrict__ bsum)
{
    __shared__ int ws[4];
    int idx = blockIdx.x * 256 + threadIdx.x;
    int v = (idx < N_NODES) ? deg[idx] : 0;
#pragma unroll
    for (int ofs = 1; ofs < 64; ofs <<= 1) v += __shfl_xor(v, ofs, 64);
    if ((threadIdx.x & 63) == 0) ws[threadIdx.x >> 6] = v;
    __syncthreads();
    if (threadIdx.x == 0) bsum[blockIdx.x] = ws[0] + ws[1] + ws[2] + ws[3];
}

__global__ __launch_bounds__(256) void scan2_kernel(const int* __restrict__ deg,
                                                    const int* __restrict__ bsum,
                                                    int* __restrict__ offs,
                                                    int* __restrict__ cur)
{
    __shared__ int wsum[4];
    __shared__ int base_s;
    const int t = threadIdx.x, lane = t & 63, w = t >> 6;

    int p = 0;
    for (int i = t; i < blockIdx.x; i += 256) p += bsum[i];
#pragma unroll
    for (int ofs = 1; ofs < 64; ofs <<= 1) p += __shfl_xor(p, ofs, 64);
    if (lane == 0) wsum[w] = p;
    __syncthreads();
    if (t == 0) base_s = wsum[0] + wsum[1] + wsum[2] + wsum[3];
    __syncthreads();

    int idx = blockIdx.x * 256 + t;
    int v = (idx < N_NODES) ? deg[idx] : 0;
    int x = v;
#pragma unroll
    for (int d = 1; d < 64; d <<= 1) {
        int y = __shfl_up(x, d, 64);
        if (lane >= d) x += y;
    }
    __syncthreads();
    if (lane == 63) wsum[w] = x;
    __syncthreads();
    int pre = base_s;
    for (int i = 0; i < w; ++i) pre += wsum[i];
    int excl = pre + x - v;
    if (idx < N_NODES) { offs[idx] = excl; cur[idx] = excl; }
}

// scatter writes source-node kv8 DWORD offset (col*64) directly
__global__ void scatter_kernel(const int* __restrict__ row, const int* __restrict__ col,
                               int* __restrict__ cursor, int* __restrict__ colw)
{
    int e = blockIdx.x * 256 + threadIdx.x;
    if (e < N_EDGES) {
        int pos = atomicAdd(cursor + row[e], 1);
        colw[pos] = col[e] * 64;
    }
}

// ---------------- fused attention (bf16 q, fp8 packed k/v), one wave per node ----
// kv8 row: 64 dwords; dword l = {k[2l],k[2l+1],v[2l],v[2l+1]} fp8-e4m3.
// Lane l owns cols 2l,2l+1 -> exactly dword l: ONE gather per edge per lane.
// Scores ~N(0,0.33^2) -> exp() w/o max-subtraction safe; /z normalizes.
__global__ __launch_bounds__(256) void attn_kernel(
    const unsigned short* __restrict__ qb, const unsigned* __restrict__ kv8,
    const int* __restrict__ colw, const int* __restrict__ offs,
    const int* __restrict__ deg, unsigned short* __restrict__ aob)
{
    const int node = blockIdx.x * 4 + (threadIdx.x >> 6);
    const int lane = threadIdx.x & 63;
    const int c0 = 2 * lane;
    const int start = offs[node];
    const int d = deg[node];

    unsigned qu = *(const unsigned*)(qb + (size_t)node * 128 + c0);
    float q0 = __uint_as_float(qu << 16);
    float q1 = __uint_as_float(qu & 0xffff0000u);
    float z0 = 0.f, z1 = 0.f, o0 = 0.f, o1 = 0.f;

#define ATTN_EDGE_W(W)                                                  \
    {                                                                   \
        float p0 = q0 * __builtin_amdgcn_cvt_f32_fp8((int)(W), 0);      \
        float p1 = q1 * __builtin_amdgcn_cvt_f32_fp8((int)(W), 1);      \
        _Pragma("unroll")                                               \
        for (int ofs = 4; ofs < 64; ofs <<= 1) {                        \
            p0 += __shfl_xor(p0, ofs, 64);                              \
            p1 += __shfl_xor(p1, ofs, 64);                              \
        }                                                               \
        float e0 = __expf(p0), e1 = __expf(p1);                         \
        z0 += e0; z1 += e1;                                             \
        o0 = fmaf(e0, __builtin_amdgcn_cvt_f32_fp8((int)(W), 2), o0);   \
        o1 = fmaf(e1, __builtin_amdgcn_cvt_f32_fp8((int)(W), 3), o1);   \
    }

    for (int base = 0; base < d; base += 64) {
        const int nrem = min(64, d - base);
        int cls = 0;
        if (lane < nrem) cls = colw[start + base + lane];   // pre-scaled *64
        int j = 0;
        for (; j + 8 <= nrem; j += 8) {
            unsigned w[8];
#pragma unroll
            for (int u = 0; u < 8; ++u) {
                int cs = __shfl(cls, j + u, 64);
                w[u] = kv8[cs + lane];
            }
#pragma unroll
            for (int u = 0; u < 8; ++u) ATTN_EDGE_W(w[u]);
        }
        for (; j < nrem; ++j) {
            int cs = __shfl(cls, j, 64);
            unsigned w = kv8[cs + lane];
            ATTN_EDGE_W(w);
        }
    }
    float r0 = (d > 0) ? o0 / z0 : 0.f;
    float r1 = (d > 0) ? o1 / z1 : 0.f;
    *(unsigned*)(aob + (size_t)node * HID + c0) =
        (unsigned)f2b(r0) | ((unsigned)f2b(r1) << 16);
}

// ---------------- BN apply (+ optional exact GELU), float4 vectorized ----------------
template<typename TO, bool ACT>
__global__ void bn_kernel(const float* __restrict__ x, const float* __restrict__ st,
                          const float* __restrict__ g, const float* __restrict__ b,
                          TO* __restrict__ out)
{
    const int i = (blockIdx.x * 256 + threadIdx.x) * 4;
    const int c = i & (HID - 1);
    float4 xv = *(const float4*)(x + i);
    float v[4] = {xv.x, xv.y, xv.z, xv.w};
#pragma unroll
    for (int u = 0; u < 4; ++u) {
        const int cc = c + u;
        float mu  = st[cc] * (1.0f / N_NODES);
        float var = st[HID + cc] * (1.0f / N_NODES) - mu * mu;
        float val = (v[u] - mu) * rsqrtf(var + 1e-5f) * g[cc] + b[cc];
        if constexpr (ACT) val = 0.5f * val * (1.0f + erff(val * 0.70710678118654752f));
        v[u] = val;
    }
    if constexpr (sizeof(TO) == 4) {
        *(float4*)((float*)out + i) = (float4){v[0], v[1], v[2], v[3]};
    } else {
        short4v w;
        w[0] = (short)f2b(v[0]); w[1] = (short)f2b(v[1]);
        w[2] = (short)f2b(v[2]); w[3] = (short)f2b(v[3]);
        *(short4v*)((unsigned short*)out + i) = w;
    }
}

extern "C" void kernel_launch(void* const* d_in, const int* in_sizes, int n_in,
                              void* d_out, int out_size, void* d_ws, size_t ws_size,
                              hipStream_t stream)
{
    const float* h   = (const float*)d_in[0];
    const int*   row = (const int*)d_in[1];
    const int*   col = (const int*)d_in[2];
    const float* Wq  = (const float*)d_in[3];
    const float* bq  = (const float*)d_in[4];
    const float* Wk  = (const float*)d_in[5];
    const float* bk  = (const float*)d_in[6];
    const float* Wv  = (const float*)d_in[7];
    const float* bv  = (const float*)d_in[8];
    const float* Wo  = (const float*)d_in[9];
    const float* bo  = (const float*)d_in[10];
    const float* W1  = (const float*)d_in[11];
    const float* bf1 = (const float*)d_in[12];
    const float* W2  = (const float*)d_in[13];
    const float* bf2 = (const float*)d_in[14];
    const float* g1  = (const float*)d_in[15];
    const float* b1  = (const float*)d_in[16];
    const float* g2  = (const float*)d_in[17];
    const float* b2  = (const float*)d_in[18];

    float* out = (float*)d_out;
    char*  ws  = (char*)d_ws;

    unsigned short* qb   = (unsigned short*)(ws + OFF_QB);
    unsigned char*  kv8  = (unsigned char*)(ws + OFF_KV8);
    unsigned short* aob  = (unsigned short*)(ws + OFF_AOB);
    unsigned short* xb   = (unsigned short*)(ws + OFF_XB);
    unsigned short* tb   = (unsigned short*)(ws + OFF_TB);
    unsigned short* hb   = (unsigned short*)(ws + OFF_HB);
    unsigned short* WTqkv= (unsigned short*)(ws + OFF_WQKV);
    unsigned short* WTo  = (unsigned short*)(ws + OFF_WTO);
    unsigned short* WT1  = (unsigned short*)(ws + OFF_WT1);
    unsigned short* WT2  = (unsigned short*)(ws + OFF_WT2);
    float* bqkv = (float*)(ws + OFF_BQKV);
    int*   deg  = (int*)(ws + OFF_DEG);
    int*   offs = (int*)(ws + OFF_OFFS);
    int*   cur  = (int*)(ws + OFF_CUR);
    int*   colw = (int*)(ws + OFF_COLW);
    int*   bsum = (int*)(ws + OFF_BSUM);
    float* st1  = (float*)(ws + OFF_ST);
    float* st2  = st1 + 256;

    hipMemsetAsync(ws + OFF_DEG, 0, (size_t)N_NODES * 4, stream);
    hipMemsetAsync(ws + OFF_ST,  0, 2048, stream);

    dim3 blk(256);
    const int nScanBlocks = (N_NODES + 255) / 256;  // 157

    wt_kernel<<<dim3(512), blk, 0, stream>>>(Wq, Wk, Wv, Wo, W1, W2, bq, bk, bv,
                                             WTqkv, WTo, WT1, WT2, bqkv);
    h2b_kernel<<<dim3(2500), blk, 0, stream>>>(h, hb);

    // fused QKV projection: q -> qb (bf16), k/v -> kv8 (fp8 packed)
    mm_kernel<unsigned short, void, 128, 384, false, false, true>
        <<<dim3(625, 3), blk, 0, stream>>>(hb, WTqkv, bqkv, nullptr, qb, kv8, nullptr);

    // CSR build
    count_kernel<<<dim3(N_EDGES / 256), blk, 0, stream>>>(row, deg);
    bsum_kernel<<<dim3(nScanBlocks), blk, 0, stream>>>(deg, bsum);
    scan2_kernel<<<dim3(nScanBlocks), blk, 0, stream>>>(deg, bsum, offs, cur);
    scatter_kernel<<<dim3(N_EDGES / 256), blk, 0, stream>>>(row, col, cur, colw);

    // fused attention
    attn_kernel<<<dim3(N_NODES / 4), blk, 0, stream>>>(qb, (const unsigned*)kv8,
                                                       colw, offs, deg, aob);

    // output projection + residual(hb) -> x0 (f32, d_out), fused BN1 stats
    mm_kernel<float, unsigned short, 128, 128, false, true, false>
        <<<dim3(625, 1), blk, 0, stream>>>(aob, WTo, bo, hb, out, nullptr, st1);

    // BN1 + GELU -> x (bf16)
    bn_kernel<unsigned short, true>
        <<<dim3(N_NODES * HID / 1024), blk, 0, stream>>>(out, st1, g1, b1, xb);

    // FFN1: x @ W1 + b -> GELU -> t (bf16)
    mm_kernel<unsigned short, void, 128, 256, true, false, false>
        <<<dim3(625, 2), blk, 0, stream>>>(xb, WT1, bf1, nullptr, tb, nullptr, nullptr);

    // FFN2: t @ W2 + b + x -> y0 (f32, d_out), fused BN2 stats
    mm_kernel<float, unsigned short, 256, 128, false, true, false>
        <<<dim3(625, 1), blk, 0, stream>>>(tb, WT2, bf2, xb, out, nullptr, st2);

    // BN2 -> final output (in place on d_out)
    bn_kernel<float, false>
        <<<dim3(N_NODES * HID / 1024), blk, 0, stream>>>(out, st2, g2, b2, out);
}

// Round 7
// 227.092 us; speedup vs baseline: 1.3493x; 1.1374x over previous
//
#include <hip/hip_runtime.h>

#define N_NODES 40000
#define N_EDGES 640000
#define HID 128
#define NHEAD 8

typedef __attribute__((ext_vector_type(8))) short short8;
typedef __attribute__((ext_vector_type(4))) short short4v;
typedef __attribute__((ext_vector_type(4))) float f32x4;

// ---------------- workspace layout (bytes) ----------------
static constexpr size_t OFF_QB   = 0;          // [40000][128] bf16 head-major q (pre-scaled)
static constexpr size_t OFF_KV8  = 10240000;   // [40000][256B]: k fp8 head-major 0..127, v 128..255
static constexpr size_t OFF_AOB  = 20480000;   // [40000][128] bf16 head-major attn out
static constexpr size_t OFF_XB   = 30720000;   // [40000][128] bf16
static constexpr size_t OFF_TB   = 40960000;   // [40000][256] bf16
static constexpr size_t OFF_HB   = 61440000;   // [40000][128] bf16
static constexpr size_t OFF_WQKV = 71680000;   // [384][128] bf16 (rows permuted head-major)
static constexpr size_t OFF_WTO  = 71778304;   // [128][128] bf16 (k-index permuted)
static constexpr size_t OFF_WT1  = 71811072;   // [256][128] bf16
static constexpr size_t OFF_WT2  = 71876608;   // [128][256] bf16
static constexpr size_t OFF_BQKV = 71942144;   // 384 f32 (permuted)
static constexpr size_t OFF_DEG  = 72000000;   // N*4
static constexpr size_t OFF_OFFS = 72160000;
static constexpr size_t OFF_CUR  = 72320000;
static constexpr size_t OFF_COLW = 72480000;   // E*4
static constexpr size_t OFF_BSUM = 75040000;   // 157*4
static constexpr size_t OFF_ST   = 75041024;   // 512 f32
// total ~75.05 MB

__device__ inline unsigned short f2b(float f) {
    unsigned x = __float_as_uint(f);
    unsigned r = x + 0x7fffu + ((x >> 16) & 1u);   // RNE
    return (unsigned short)(r >> 16);
}
__device__ inline float b2f(unsigned short u) {
    return __uint_as_float(((unsigned)u) << 16);
}
__device__ inline unsigned char f2fp8(float f) {
    return (unsigned char)(__builtin_amdgcn_cvt_pk_fp8_f32(f, f, 0, false) & 0xff);
}
// orig col n (= d*8+h) -> head-major position h*16+d
__device__ inline int hmpos(int n) { return (n & 7) * 16 + (n >> 3); }

// ---------------- h -> bf16 ----------------
__global__ void h2b_kernel(const float* __restrict__ h, unsigned short* __restrict__ hb)
{
    const int i = (blockIdx.x * 256 + threadIdx.x) * 8;
    float4 f0 = *(const float4*)(h + i);
    float4 f1 = *(const float4*)(h + i + 4);
    short8 w;
    w[0] = (short)f2b(f0.x); w[1] = (short)f2b(f0.y);
    w[2] = (short)f2b(f0.z); w[3] = (short)f2b(f0.w);
    w[4] = (short)f2b(f1.x); w[5] = (short)f2b(f1.y);
    w[6] = (short)f2b(f1.z); w[7] = (short)f2b(f1.w);
    *(short8*)(hb + i) = w;
}

// ---------------- weight pre-transpose + bf16 convert (head-major permutes) ------
__global__ void wt_kernel(const float* __restrict__ Wq, const float* __restrict__ Wk,
                          const float* __restrict__ Wv, const float* __restrict__ Wo,
                          const float* __restrict__ W1, const float* __restrict__ W2,
                          const float* __restrict__ bq, const float* __restrict__ bk,
                          const float* __restrict__ bv,
                          unsigned short* __restrict__ WTqkv, unsigned short* __restrict__ WTo,
                          unsigned short* __restrict__ WT1, unsigned short* __restrict__ WT2,
                          float* __restrict__ bqkv)
{
    int i = blockIdx.x * 256 + threadIdx.x;   // 0..131071
    if (i < 16384) {
        int k = i >> 7, n = i & 127;
        WTqkv[hmpos(n) * 128 + k] = f2b(0.25f * Wq[i]);            // q rows permuted
    } else if (i < 32768) {
        int j = i - 16384; int k = j >> 7, n = j & 127;
        WTqkv[(128 + hmpos(n)) * 128 + k] = f2b(Wk[j]);            // k rows permuted
    } else if (i < 49152) {
        int j = i - 32768; int k = j >> 7, n = j & 127;
        WTqkv[(256 + hmpos(n)) * 128 + k] = f2b(Wv[j]);            // v rows permuted
    } else if (i < 65536) {
        int j = i - 49152; int k = j >> 7, n = j & 127;
        WTo[n * 128 + hmpos(k)] = f2b(Wo[j]);                      // Wo k-index permuted
    } else if (i < 98304) {
        int j = i - 65536; int k = j >> 8, n = j & 255;
        WT1[n * 128 + k] = f2b(W1[j]);
    } else {
        int j = i - 98304; int k = j >> 7, n = j & 127;
        WT2[n * 256 + k] = f2b(W2[j]);
    }
    if (blockIdx.x == 0 && threadIdx.x < 384) {
        int c = threadIdx.x;
        int seg = c >> 7, n = c & 127;
        float v = (seg == 0) ? 0.25f * bq[n] : (seg == 1) ? bk[n] : bv[n];
        bqkv[seg * 128 + hmpos(n)] = v;
    }
}

// ---------------- bf16 MFMA GEMM (BM=64, BN=128, BK=128) ----------------
// C = act((A @ WT^T) + bias [+ res]); A bf16 [M][K], WT [NTOT][K] bf16.
// 256 thr = 4 waves; wave owns 32 cols, acc[4][2] of 16x16 frags.
// QKVMODE: cols are head-major positions; colOff==0 -> bf16 q, else fp8 into kv8;
// both repacked through LDS (aliasing As) for coalesced dwordx4 stores.
template<typename TC, typename TR, int K, int NTOT, bool ACT, bool STATS, bool QKVMODE>
__global__ __launch_bounds__(256) void mm_kernel(
    const unsigned short* __restrict__ A, const unsigned short* __restrict__ WT,
    const float* __restrict__ bias, const TR* __restrict__ res,
    TC* __restrict__ C, unsigned char* __restrict__ kv8, float* __restrict__ st)
{
    __shared__ unsigned short As[64][136];
    __shared__ unsigned short Bs[128][136];
    const int t = threadIdx.x;
    const int lane = t & 63, wave = t >> 6;
    const int row0 = blockIdx.x * 64;
    const int colOff = blockIdx.y * 128;

    f32x4 acc[4][2];
#pragma unroll
    for (int i = 0; i < 4; ++i)
#pragma unroll
        for (int j = 0; j < 2; ++j) acc[i][j] = (f32x4){0.f, 0.f, 0.f, 0.f};

    for (int k0 = 0; k0 < K; k0 += 128) {
        {
            const int r = t >> 2, kc = (t & 3) * 32;
            const unsigned short* ap = A + (size_t)(row0 + r) * K + k0 + kc;
#pragma unroll
            for (int i = 0; i < 4; ++i)
                *(short8*)&As[r][kc + 8 * i] = *(const short8*)(ap + 8 * i);
        }
        {
            const int n = t >> 1, kc = (t & 1) * 64;
            const unsigned short* wp = WT + (size_t)(colOff + n) * K + k0 + kc;
#pragma unroll
            for (int i = 0; i < 8; ++i)
                *(short8*)&Bs[n][kc + 8 * i] = *(const short8*)(wp + 8 * i);
        }
        __syncthreads();

#pragma unroll
        for (int ks = 0; ks < 4; ++ks) {
            const int kf = ks * 32 + (lane >> 4) * 8;
            short8 af[4], bf_[2];
#pragma unroll
            for (int mi = 0; mi < 4; ++mi)
                af[mi] = *(short8*)&As[mi * 16 + (lane & 15)][kf];
#pragma unroll
            for (int ni = 0; ni < 2; ++ni)
                bf_[ni] = *(short8*)&Bs[wave * 32 + ni * 16 + (lane & 15)][kf];
#pragma unroll
            for (int mi = 0; mi < 4; ++mi)
#pragma unroll
                for (int ni = 0; ni < 2; ++ni)
                    acc[mi][ni] = __builtin_amdgcn_mfma_f32_16x16x32_bf16(
                        af[mi], bf_[ni], acc[mi][ni], 0, 0, 0);
        }
        __syncthreads();
    }

    unsigned short* LQ  = (unsigned short*)&As[0][0];  // 64x128 ushort (16 KB)
    unsigned char*  LKV = (unsigned char*)&As[0][0];   // 64x128 bytes  (8 KB)

    float csum[2] = {0.f, 0.f}, csq[2] = {0.f, 0.f};
#pragma unroll
    for (int mi = 0; mi < 4; ++mi) {
#pragma unroll
        for (int ni = 0; ni < 2; ++ni) {
            const int lc = wave * 32 + ni * 16 + (lane & 15);   // local col 0..127
            const int c = colOff + lc;
            const float bv_ = bias[c];
#pragma unroll
            for (int reg = 0; reg < 4; ++reg) {
                const int rl = mi * 16 + (lane >> 4) * 4 + reg;  // local row 0..63
                const int r = row0 + rl;
                float val = acc[mi][ni][reg] + bv_;
                if constexpr (!__is_same(TR, void)) {
                    if constexpr (sizeof(TR) == 4)
                        val += ((const float*)res)[(size_t)r * 128 + c];
                    else
                        val += b2f(((const unsigned short*)res)[(size_t)r * 128 + c]);
                }
                if constexpr (ACT)
                    val = 0.5f * val * (1.0f + erff(val * 0.70710678118654752f));
                if constexpr (STATS) {
                    csum[ni] += val;
                    csq[ni]  += val * val;
                }
                if constexpr (QKVMODE) {
                    if (colOff == 0) LQ[rl * 128 + lc] = f2b(val);
                    else             LKV[rl * 128 + lc] = f2fp8(val);
                } else {
                    if constexpr (sizeof(TC) == 4)
                        ((float*)C)[(size_t)r * NTOT + c] = val;
                    else
                        ((unsigned short*)C)[(size_t)r * NTOT + c] = f2b(val);
                }
            }
        }
    }

    if constexpr (QKVMODE) {
        __syncthreads();
        const int rrow = t >> 2, ch = t & 3;
        if (colOff == 0) {
            uint4* dst = (uint4*)((unsigned short*)C + (size_t)(row0 + rrow) * 128 + ch * 32);
            const uint4* src = (const uint4*)(LQ + rrow * 128 + ch * 32);
            dst[0] = src[0]; dst[1] = src[1]; dst[2] = src[2]; dst[3] = src[3];
        } else {
            const int segbase = (colOff == 128) ? 0 : 128;
            uint4* dst = (uint4*)(kv8 + (size_t)(row0 + rrow) * 256 + segbase + ch * 32);
            const uint4* src = (const uint4*)(LKV + rrow * 128 + ch * 32);
            dst[0] = src[0]; dst[1] = src[1];
        }
    }

    if constexpr (STATS) {   // NTOT==128 only
#pragma unroll
        for (int ni = 0; ni < 2; ++ni) {
            float s = csum[ni], qq = csq[ni];
            s  += __shfl_xor(s, 16, 64);  s  += __shfl_xor(s, 32, 64);
            qq += __shfl_xor(qq, 16, 64); qq += __shfl_xor(qq, 32, 64);
            if (lane < 16) {
                const int c = wave * 32 + ni * 16 + lane;
                atomicAdd(st + c, s);
                atomicAdd(st + 128 + c, qq);
            }
        }
    }
}

// ---------------- CSR build ----------------
__global__ void count_kernel(const int* __restrict__ row, int* __restrict__ deg)
{
    int e = blockIdx.x * 256 + threadIdx.x;
    if (e < N_EDGES) atomicAdd(deg + row[e], 1);
}

__global__ __launch_bounds__(256) void bsum_kernel(const int* __restrict__ deg,
                                                   int* __restrict__ bsum)
{
    __shared__ int ws[4];
    int idx = blockIdx.x * 256 + threadIdx.x;
    int v = (idx < N_NODES) ? deg[idx] : 0;
#pragma unroll
    for (int ofs = 1; ofs < 64; ofs <<= 1) v += __shfl_xor(v, ofs, 64);
    if ((threadIdx.x & 63) == 0) ws[threadIdx.x >> 6] = v;
    __syncthreads();
    if (threadIdx.x == 0) bsum[blockIdx.x] = ws[0] + ws[1] + ws[2] + ws[3];
}

__global__ __launch_bounds__(256) void scan2_kernel(const int* __restrict__ deg,
                                                    const int* __restrict__ bsum,
                                                    int* __restrict__ offs,
                                                    int* __restrict__ cur)
{
    __shared__ int wsum[4];
    __shared__ int base_s;
    const int t = threadIdx.x, lane = t & 63, w = t >> 6;

    int p = 0;
    for (int i = t; i < blockIdx.x; i += 256) p += bsum[i];
#pragma unroll
    for (int ofs = 1; ofs < 64; ofs <<= 1) p += __shfl_xor(p, ofs, 64);
    if (lane == 0) wsum[w] = p;
    __syncthreads();
    if (t == 0) base_s = wsum[0] + wsum[1] + wsum[2] + wsum[3];
    __syncthreads();

    int idx = blockIdx.x * 256 + t;
    int v = (idx < N_NODES) ? deg[idx] : 0;
    int x = v;
#pragma unroll
    for (int d = 1; d < 64; d <<= 1) {
        int y = __shfl_up(x, d, 64);
        if (lane >= d) x += y;
    }
    __syncthreads();
    if (lane == 63) wsum[w] = x;
    __syncthreads();
    int pre = base_s;
    for (int i = 0; i < w; ++i) pre += wsum[i];
    int excl = pre + x - v;
    if (idx < N_NODES) { offs[idx] = excl; cur[idx] = excl; }
}

// scatter writes source-node kv8 BYTE offset (col*256) directly
__global__ void scatter_kernel(const int* __restrict__ row, const int* __restrict__ col,
                               int* __restrict__ cursor, int* __restrict__ colw)
{
    int e = blockIdx.x * 256 + threadIdx.x;
    if (e < N_EDGES) {
        int pos = atomicAdd(cursor + row[e], 1);
        colw[pos] = col[e] * 256;
    }
}

// ---------------- fused attention, head-major: zero per-edge shuffles ----------
// lane = (edge-slot es=lane>>3, head h=lane&7). Per 8-edge step each lane gathers
// 16B k + 16B v for (its edge, its head), lane-local 16-FMA dot, 1 exp, 16 o-FMAs.
// Cross-lane reduce (xor 8/16/32 over es) once per node. Scores ~N(0,0.33^2) ->
// exp() w/o max-subtraction safe; /z normalizes.
__global__ __launch_bounds__(256) void attn_kernel(
    const unsigned short* __restrict__ qh, const unsigned char* __restrict__ kv8,
    const int* __restrict__ colw, const int* __restrict__ offs,
    const int* __restrict__ deg, unsigned short* __restrict__ aob)
{
    const int node = blockIdx.x * 4 + (threadIdx.x >> 6);
    const int lane = threadIdx.x & 63;
    const int h = lane & 7;
    const int es = lane >> 3;
    const int start = offs[node];
    const int d = deg[node];

    float qv[16];
    {
        const uint4* qp = (const uint4*)(qh + (size_t)node * 128 + h * 16);
        uint4 a = qp[0], b = qp[1];
        unsigned uu[8] = {a.x, a.y, a.z, a.w, b.x, b.y, b.z, b.w};
#pragma unroll
        for (int i = 0; i < 8; ++i) {
            qv[2 * i]     = __uint_as_float(uu[i] << 16);
            qv[2 * i + 1] = __uint_as_float(uu[i] & 0xffff0000u);
        }
    }
    float z = 0.f;
    float o[16];
#pragma unroll
    for (int i = 0; i < 16; ++i) o[i] = 0.f;

    for (int base = 0; base < d; base += 64) {
        const int nrem = min(64, d - base);
        int cl = 0;
        if (lane < nrem) cl = colw[start + base + lane];
        for (int j = 0; j < nrem; j += 8) {
            const int idx = j + es;
            const int cs = __shfl(cl, idx, 64);
            const bool valid = idx < nrem;
            uint4 kw = *(const uint4*)(kv8 + cs + h * 16);
            uint4 vw = *(const uint4*)(kv8 + cs + 128 + h * 16);
            unsigned kk[4] = {kw.x, kw.y, kw.z, kw.w};
            unsigned vv[4] = {vw.x, vw.y, vw.z, vw.w};
            float p0 = 0.f, p1 = 0.f, p2 = 0.f, p3 = 0.f;
#pragma unroll
            for (int w = 0; w < 4; ++w) {
                p0 = fmaf(qv[4 * w + 0], __builtin_amdgcn_cvt_f32_fp8((int)kk[w], 0), p0);
                p1 = fmaf(qv[4 * w + 1], __builtin_amdgcn_cvt_f32_fp8((int)kk[w], 1), p1);
                p2 = fmaf(qv[4 * w + 2], __builtin_amdgcn_cvt_f32_fp8((int)kk[w], 2), p2);
                p3 = fmaf(qv[4 * w + 3], __builtin_amdgcn_cvt_f32_fp8((int)kk[w], 3), p3);
            }
            const float p = (p0 + p1) + (p2 + p3);
            const float e = valid ? __expf(p) : 0.f;
            z += e;
#pragma unroll
            for (int w = 0; w < 4; ++w) {
                o[4 * w + 0] = fmaf(e, __builtin_amdgcn_cvt_f32_fp8((int)vv[w], 0), o[4 * w + 0]);
                o[4 * w + 1] = fmaf(e, __builtin_amdgcn_cvt_f32_fp8((int)vv[w], 1), o[4 * w + 1]);
                o[4 * w + 2] = fmaf(e, __builtin_amdgcn_cvt_f32_fp8((int)vv[w], 2), o[4 * w + 2]);
                o[4 * w + 3] = fmaf(e, __builtin_amdgcn_cvt_f32_fp8((int)vv[w], 3), o[4 * w + 3]);
            }
        }
    }

#pragma unroll
    for (int m = 8; m < 64; m <<= 1) {
        z += __shfl_xor(z, m, 64);
#pragma unroll
        for (int i = 0; i < 16; ++i) o[i] += __shfl_xor(o[i], m, 64);
    }
    if (es == 0) {
        const float rz = (d > 0) ? 1.f / z : 0.f;
        short8 w0, w1;
#pragma unroll
        for (int i = 0; i < 8; ++i) w0[i] = (short)f2b(o[i] * rz);
#pragma unroll
        for (int i = 0; i < 8; ++i) w1[i] = (short)f2b(o[8 + i] * rz);
        *(short8*)(aob + (size_t)node * 128 + h * 16)     = w0;
        *(short8*)(aob + (size_t)node * 128 + h * 16 + 8) = w1;
    }
}

// ---------------- BN apply (+ optional exact GELU), float4 vectorized ----------------
template<typename TO, bool ACT>
__global__ void bn_kernel(const float* __restrict__ x, const float* __restrict__ st,
                          const float* __restrict__ g, const float* __restrict__ b,
                          TO* __restrict__ out)
{
    const int i = (blockIdx.x * 256 + threadIdx.x) * 4;
    const int c = i & (HID - 1);
    float4 xv = *(const float4*)(x + i);
    float v[4] = {xv.x, xv.y, xv.z, xv.w};
#pragma unroll
    for (int u = 0; u < 4; ++u) {
        const int cc = c + u;
        float mu  = st[cc] * (1.0f / N_NODES);
        float var = st[HID + cc] * (1.0f / N_NODES) - mu * mu;
        float val = (v[u] - mu) * rsqrtf(var + 1e-5f) * g[cc] + b[cc];
        if constexpr (ACT) val = 0.5f * val * (1.0f + erff(val * 0.70710678118654752f));
        v[u] = val;
    }
    if constexpr (sizeof(TO) == 4) {
        *(float4*)((float*)out + i) = (float4){v[0], v[1], v[2], v[3]};
    } else {
        short4v w;
        w[0] = (short)f2b(v[0]); w[1] = (short)f2b(v[1]);
        w[2] = (short)f2b(v[2]); w[3] = (short)f2b(v[3]);
        *(short4v*)((unsigned short*)out + i) = w;
    }
}

extern "C" void kernel_launch(void* const* d_in, const int* in_sizes, int n_in,
                              void* d_out, int out_size, void* d_ws, size_t ws_size,
                              hipStream_t stream)
{
    const float* h   = (const float*)d_in[0];
    const int*   row = (const int*)d_in[1];
    const int*   col = (const int*)d_in[2];
    const float* Wq  = (const float*)d_in[3];
    const float* bq  = (const float*)d_in[4];
    const float* Wk  = (const float*)d_in[5];
    const float* bk  = (const float*)d_in[6];
    const float* Wv  = (const float*)d_in[7];
    const float* bv  = (const float*)d_in[8];
    const float* Wo  = (const float*)d_in[9];
    const float* bo  = (const float*)d_in[10];
    const float* W1  = (const float*)d_in[11];
    const float* bf1 = (const float*)d_in[12];
    const float* W2  = (const float*)d_in[13];
    const float* bf2 = (const float*)d_in[14];
    const float* g1  = (const float*)d_in[15];
    const float* b1  = (const float*)d_in[16];
    const float* g2  = (const float*)d_in[17];
    const float* b2  = (const float*)d_in[18];

    float* out = (float*)d_out;
    char*  ws  = (char*)d_ws;

    unsigned short* qh   = (unsigned short*)(ws + OFF_QB);
    unsigned char*  kv8  = (unsigned char*)(ws + OFF_KV8);
    unsigned short* aob  = (unsigned short*)(ws + OFF_AOB);
    unsigned short* xb   = (unsigned short*)(ws + OFF_XB);
    unsigned short* tb   = (unsigned short*)(ws + OFF_TB);
    unsigned short* hb   = (unsigned short*)(ws + OFF_HB);
    unsigned short* WTqkv= (unsigned short*)(ws + OFF_WQKV);
    unsigned short* WTo  = (unsigned short*)(ws + OFF_WTO);
    unsigned short* WT1  = (unsigned short*)(ws + OFF_WT1);
    unsigned short* WT2  = (unsigned short*)(ws + OFF_WT2);
    float* bqkv = (float*)(ws + OFF_BQKV);
    int*   deg  = (int*)(ws + OFF_DEG);
    int*   offs = (int*)(ws + OFF_OFFS);
    int*   cur  = (int*)(ws + OFF_CUR);
    int*   colw = (int*)(ws + OFF_COLW);
    int*   bsum = (int*)(ws + OFF_BSUM);
    float* st1  = (float*)(ws + OFF_ST);
    float* st2  = st1 + 256;

    hipMemsetAsync(ws + OFF_DEG, 0, (size_t)N_NODES * 4, stream);
    hipMemsetAsync(ws + OFF_ST,  0, 2048, stream);

    dim3 blk(256);
    const int nScanBlocks = (N_NODES + 255) / 256;  // 157

    wt_kernel<<<dim3(512), blk, 0, stream>>>(Wq, Wk, Wv, Wo, W1, W2, bq, bk, bv,
                                             WTqkv, WTo, WT1, WT2, bqkv);
    h2b_kernel<<<dim3(2500), blk, 0, stream>>>(h, hb);

    // fused QKV projection: q -> qh (bf16 head-major), k/v -> kv8 (fp8 head-major)
    mm_kernel<unsigned short, void, 128, 384, false, false, true>
        <<<dim3(625, 3), blk, 0, stream>>>(hb, WTqkv, bqkv, nullptr, qh, kv8, nullptr);

    // CSR build
    count_kernel<<<dim3(N_EDGES / 256), blk, 0, stream>>>(row, deg);
    bsum_kernel<<<dim3(nScanBlocks), blk, 0, stream>>>(deg, bsum);
    scan2_kernel<<<dim3(nScanBlocks), blk, 0, stream>>>(deg, bsum, offs, cur);
    scatter_kernel<<<dim3(N_EDGES / 256), blk, 0, stream>>>(row, col, cur, colw);

    // fused attention
    attn_kernel<<<dim3(N_NODES / 4), blk, 0, stream>>>(qh, kv8, colw, offs, deg, aob);

    // output projection + residual(hb) -> x0 (f32, d_out), fused BN1 stats
    mm_kernel<float, unsigned short, 128, 128, false, true, false>
        <<<dim3(625, 1), blk, 0, stream>>>(aob, WTo, bo, hb, out, nullptr, st1);

    // BN1 + GELU -> x (bf16)
    bn_kernel<unsigned short, true>
        <<<dim3(N_NODES * HID / 1024), blk, 0, stream>>>(out, st1, g1, b1, xb);

    // FFN1: x @ W1 + b -> GELU -> t (bf16)
    mm_kernel<unsigned short, void, 128, 256, true, false, false>
        <<<dim3(625, 2), blk, 0, stream>>>(xb, WT1, bf1, nullptr, tb, nullptr, nullptr);

    // FFN2: t @ W2 + b + x -> y0 (f32, d_out), fused BN2 stats
    mm_kernel<float, unsigned short, 256, 128, false, true, false>
        <<<dim3(625, 1), blk, 0, stream>>>(tb, WT2, bf2, xb, out, nullptr, st2);

    // BN2 -> final output (in place on d_out)
    bn_kernel<float, false>
        <<<dim3(N_NODES * HID / 1024), blk, 0, stream>>>(out, st2, g2, b2, out);
}

// Round 8
// 221.091 us; speedup vs baseline: 1.3859x; 1.0271x over previous
//
#include <hip/hip_runtime.h>

#define N_NODES 40000
#define N_EDGES 640000
#define HID 128
#define NHEAD 8

typedef __attribute__((ext_vector_type(8))) short short8;
typedef __attribute__((ext_vector_type(4))) short short4v;
typedef __attribute__((ext_vector_type(4))) float f32x4;

// ---------------- workspace layout (bytes) ----------------
static constexpr size_t OFF_QB   = 0;          // [40000][128] bf16 head-major q (pre-scaled)
static constexpr size_t OFF_KV8  = 10240000;   // [40000][256B]: k fp8 head-major 0..127, v 128..255
static constexpr size_t OFF_AOB  = 20480000;   // [40000][128] bf16 head-major attn out
static constexpr size_t OFF_XB   = 30720000;   // [40000][128] bf16
static constexpr size_t OFF_TB   = 40960000;   // [40000][256] bf16
static constexpr size_t OFF_HB   = 61440000;   // [40000][128] bf16
static constexpr size_t OFF_WQKV = 71680000;   // [384][128] bf16 (rows permuted head-major)
static constexpr size_t OFF_WTO  = 71778304;   // [128][128] bf16 (k-index permuted)
static constexpr size_t OFF_WT1  = 71811072;   // [256][128] bf16
static constexpr size_t OFF_WT2  = 71876608;   // [128][256] bf16
static constexpr size_t OFF_BQKV = 71942144;   // 384 f32 (permuted)
static constexpr size_t OFF_DEG  = 72000000;   // N*4
static constexpr size_t OFF_OFFS = 72160000;
static constexpr size_t OFF_CUR  = 72320000;
static constexpr size_t OFF_COLW = 72480000;   // E*4
static constexpr size_t OFF_BSUM = 75040000;   // 157*4
static constexpr size_t OFF_ST   = 75041024;   // 512 f32
// total ~75.05 MB

__device__ inline unsigned short f2b(float f) {
    unsigned x = __float_as_uint(f);
    unsigned r = x + 0x7fffu + ((x >> 16) & 1u);   // RNE
    return (unsigned short)(r >> 16);
}
__device__ inline float b2f(unsigned short u) {
    return __uint_as_float(((unsigned)u) << 16);
}
__device__ inline unsigned char f2fp8(float f) {
    return (unsigned char)(__builtin_amdgcn_cvt_pk_fp8_f32(f, f, 0, false) & 0xff);
}
// orig col n (= d*8+h) -> head-major position h*16+d
__device__ inline int hmpos(int n) { return (n & 7) * 16 + (n >> 3); }

// ---------------- h -> bf16 ----------------
__global__ void h2b_kernel(const float* __restrict__ h, unsigned short* __restrict__ hb)
{
    const int i = (blockIdx.x * 256 + threadIdx.x) * 8;
    float4 f0 = *(const float4*)(h + i);
    float4 f1 = *(const float4*)(h + i + 4);
    short8 w;
    w[0] = (short)f2b(f0.x); w[1] = (short)f2b(f0.y);
    w[2] = (short)f2b(f0.z); w[3] = (short)f2b(f0.w);
    w[4] = (short)f2b(f1.x); w[5] = (short)f2b(f1.y);
    w[6] = (short)f2b(f1.z); w[7] = (short)f2b(f1.w);
    *(short8*)(hb + i) = w;
}

// ---------------- weight pre-transpose + bf16 convert (head-major permutes) ------
// Also zeroes deg[] and st[] (replaces two in-graph hipMemsetAsync fill kernels
// that each cost ~40 us of dispatch/drain time -- round 7 profile).
__global__ void wt_kernel(const float* __restrict__ Wq, const float* __restrict__ Wk,
                          const float* __restrict__ Wv, const float* __restrict__ Wo,
                          const float* __restrict__ W1, const float* __restrict__ W2,
                          const float* __restrict__ bq, const float* __restrict__ bk,
                          const float* __restrict__ bv,
                          unsigned short* __restrict__ WTqkv, unsigned short* __restrict__ WTo,
                          unsigned short* __restrict__ WT1, unsigned short* __restrict__ WT2,
                          float* __restrict__ bqkv,
                          int* __restrict__ deg, float* __restrict__ st)
{
    int i = blockIdx.x * 256 + threadIdx.x;   // 0..131071
    if (i < N_NODES) deg[i] = 0;
    if (i < 512) st[i] = 0.f;
    if (i < 16384) {
        int k = i >> 7, n = i & 127;
        WTqkv[hmpos(n) * 128 + k] = f2b(0.25f * Wq[i]);            // q rows permuted
    } else if (i < 32768) {
        int j = i - 16384; int k = j >> 7, n = j & 127;
        WTqkv[(128 + hmpos(n)) * 128 + k] = f2b(Wk[j]);            // k rows permuted
    } else if (i < 49152) {
        int j = i - 32768; int k = j >> 7, n = j & 127;
        WTqkv[(256 + hmpos(n)) * 128 + k] = f2b(Wv[j]);            // v rows permuted
    } else if (i < 65536) {
        int j = i - 49152; int k = j >> 7, n = j & 127;
        WTo[n * 128 + hmpos(k)] = f2b(Wo[j]);                      // Wo k-index permuted
    } else if (i < 98304) {
        int j = i - 65536; int k = j >> 8, n = j & 255;
        WT1[n * 128 + k] = f2b(W1[j]);
    } else {
        int j = i - 98304; int k = j >> 7, n = j & 127;
        WT2[n * 256 + k] = f2b(W2[j]);
    }
    if (blockIdx.x == 0 && threadIdx.x < 384) {
        int c = threadIdx.x;
        int seg = c >> 7, n = c & 127;
        float v = (seg == 0) ? 0.25f * bq[n] : (seg == 1) ? bk[n] : bv[n];
        bqkv[seg * 128 + hmpos(n)] = v;
    }
}

// ---------------- bf16 MFMA GEMM (BM=64, BN=128, BK=128) ----------------
// C = act((A @ WT^T) + bias [+ res]); A bf16 [M][K], WT [NTOT][K] bf16.
// 256 thr = 4 waves; wave owns 32 cols, acc[4][2] of 16x16 frags.
// QKVMODE: cols are head-major positions; colOff==0 -> bf16 q, else fp8 into kv8;
// both repacked through LDS (aliasing As) for coalesced dwordx4 stores.
template<typename TC, typename TR, int K, int NTOT, bool ACT, bool STATS, bool QKVMODE>
__global__ __launch_bounds__(256) void mm_kernel(
    const unsigned short* __restrict__ A, const unsigned short* __restrict__ WT,
    const float* __restrict__ bias, const TR* __restrict__ res,
    TC* __restrict__ C, unsigned char* __restrict__ kv8, float* __restrict__ st)
{
    __shared__ unsigned short As[64][136];
    __shared__ unsigned short Bs[128][136];
    const int t = threadIdx.x;
    const int lane = t & 63, wave = t >> 6;
    const int row0 = blockIdx.x * 64;
    const int colOff = blockIdx.y * 128;

    f32x4 acc[4][2];
#pragma unroll
    for (int i = 0; i < 4; ++i)
#pragma unroll
        for (int j = 0; j < 2; ++j) acc[i][j] = (f32x4){0.f, 0.f, 0.f, 0.f};

    for (int k0 = 0; k0 < K; k0 += 128) {
        {
            const int r = t >> 2, kc = (t & 3) * 32;
            const unsigned short* ap = A + (size_t)(row0 + r) * K + k0 + kc;
#pragma unroll
            for (int i = 0; i < 4; ++i)
                *(short8*)&As[r][kc + 8 * i] = *(const short8*)(ap + 8 * i);
        }
        {
            const int n = t >> 1, kc = (t & 1) * 64;
            const unsigned short* wp = WT + (size_t)(colOff + n) * K + k0 + kc;
#pragma unroll
            for (int i = 0; i < 8; ++i)
                *(short8*)&Bs[n][kc + 8 * i] = *(const short8*)(wp + 8 * i);
        }
        __syncthreads();

#pragma unroll
        for (int ks = 0; ks < 4; ++ks) {
            const int kf = ks * 32 + (lane >> 4) * 8;
            short8 af[4], bf_[2];
#pragma unroll
            for (int mi = 0; mi < 4; ++mi)
                af[mi] = *(short8*)&As[mi * 16 + (lane & 15)][kf];
#pragma unroll
            for (int ni = 0; ni < 2; ++ni)
                bf_[ni] = *(short8*)&Bs[wave * 32 + ni * 16 + (lane & 15)][kf];
#pragma unroll
            for (int mi = 0; mi < 4; ++mi)
#pragma unroll
                for (int ni = 0; ni < 2; ++ni)
                    acc[mi][ni] = __builtin_amdgcn_mfma_f32_16x16x32_bf16(
                        af[mi], bf_[ni], acc[mi][ni], 0, 0, 0);
        }
        __syncthreads();
    }

    unsigned short* LQ  = (unsigned short*)&As[0][0];  // 64x128 ushort (16 KB)
    unsigned char*  LKV = (unsigned char*)&As[0][0];   // 64x128 bytes  (8 KB)

    float csum[2] = {0.f, 0.f}, csq[2] = {0.f, 0.f};
#pragma unroll
    for (int mi = 0; mi < 4; ++mi) {
#pragma unroll
        for (int ni = 0; ni < 2; ++ni) {
            const int lc = wave * 32 + ni * 16 + (lane & 15);   // local col 0..127
            const int c = colOff + lc;
            const float bv_ = bias[c];
#pragma unroll
            for (int reg = 0; reg < 4; ++reg) {
                const int rl = mi * 16 + (lane >> 4) * 4 + reg;  // local row 0..63
                const int r = row0 + rl;
                float val = acc[mi][ni][reg] + bv_;
                if constexpr (!__is_same(TR, void)) {
                    if constexpr (sizeof(TR) == 4)
                        val += ((const float*)res)[(size_t)r * 128 + c];
                    else
                        val += b2f(((const unsigned short*)res)[(size_t)r * 128 + c]);
                }
                if constexpr (ACT)
                    val = 0.5f * val * (1.0f + erff(val * 0.70710678118654752f));
                if constexpr (STATS) {
                    csum[ni] += val;
                    csq[ni]  += val * val;
                }
                if constexpr (QKVMODE) {
                    if (colOff == 0) LQ[rl * 128 + lc] = f2b(val);
                    else             LKV[rl * 128 + lc] = f2fp8(val);
                } else {
                    if constexpr (sizeof(TC) == 4)
                        ((float*)C)[(size_t)r * NTOT + c] = val;
                    else
                        ((unsigned short*)C)[(size_t)r * NTOT + c] = f2b(val);
                }
            }
        }
    }

    if constexpr (QKVMODE) {
        __syncthreads();
        const int rrow = t >> 2, ch = t & 3;
        if (colOff == 0) {
            uint4* dst = (uint4*)((unsigned short*)C + (size_t)(row0 + rrow) * 128 + ch * 32);
            const uint4* src = (const uint4*)(LQ + rrow * 128 + ch * 32);
            dst[0] = src[0]; dst[1] = src[1]; dst[2] = src[2]; dst[3] = src[3];
        } else {
            const int segbase = (colOff == 128) ? 0 : 128;
            uint4* dst = (uint4*)(kv8 + (size_t)(row0 + rrow) * 256 + segbase + ch * 32);
            const uint4* src = (const uint4*)(LKV + rrow * 128 + ch * 32);
            dst[0] = src[0]; dst[1] = src[1];
        }
    }

    if constexpr (STATS) {   // NTOT==128 only
#pragma unroll
        for (int ni = 0; ni < 2; ++ni) {
            float s = csum[ni], qq = csq[ni];
            s  += __shfl_xor(s, 16, 64);  s  += __shfl_xor(s, 32, 64);
            qq += __shfl_xor(qq, 16, 64); qq += __shfl_xor(qq, 32, 64);
            if (lane < 16) {
                const int c = wave * 32 + ni * 16 + lane;
                atomicAdd(st + c, s);
                atomicAdd(st + 128 + c, qq);
            }
        }
    }
}

// ---------------- CSR build ----------------
__global__ void count_kernel(const int* __restrict__ row, int* __restrict__ deg)
{
    int e = blockIdx.x * 256 + threadIdx.x;
    if (e < N_EDGES) atomicAdd(deg + row[e], 1);
}

__global__ __launch_bounds__(256) void bsum_kernel(const int* __restrict__ deg,
                                                   int* __restrict__ bsum)
{
    __shared__ int ws[4];
    int idx = blockIdx.x * 256 + threadIdx.x;
    int v = (idx < N_NODES) ? deg[idx] : 0;
#pragma unroll
    for (int ofs = 1; ofs < 64; ofs <<= 1) v += __shfl_xor(v, ofs, 64);
    if ((threadIdx.x & 63) == 0) ws[threadIdx.x >> 6] = v;
    __syncthreads();
    if (threadIdx.x == 0) bsum[blockIdx.x] = ws[0] + ws[1] + ws[2] + ws[3];
}

__global__ __launch_bounds__(256) void scan2_kernel(const int* __restrict__ deg,
                                                    const int* __restrict__ bsum,
                                                    int* __restrict__ offs,
                                                    int* __restrict__ cur)
{
    __shared__ int wsum[4];
    __shared__ int base_s;
    const int t = threadIdx.x, lane = t & 63, w = t >> 6;

    int p = 0;
    for (int i = t; i < blockIdx.x; i += 256) p += bsum[i];
#pragma unroll
    for (int ofs = 1; ofs < 64; ofs <<= 1) p += __shfl_xor(p, ofs, 64);
    if (lane == 0) wsum[w] = p;
    __syncthreads();
    if (t == 0) base_s = wsum[0] + wsum[1] + wsum[2] + wsum[3];
    __syncthreads();

    int idx = blockIdx.x * 256 + t;
    int v = (idx < N_NODES) ? deg[idx] : 0;
    int x = v;
#pragma unroll
    for (int d = 1; d < 64; d <<= 1) {
        int y = __shfl_up(x, d, 64);
        if (lane >= d) x += y;
    }
    __syncthreads();
    if (lane == 63) wsum[w] = x;
    __syncthreads();
    int pre = base_s;
    for (int i = 0; i < w; ++i) pre += wsum[i];
    int excl = pre + x - v;
    if (idx < N_NODES) { offs[idx] = excl; cur[idx] = excl; }
}

// scatter writes source-node kv8 BYTE offset (col*256) directly
__global__ void scatter_kernel(const int* __restrict__ row, const int* __restrict__ col,
                               int* __restrict__ cursor, int* __restrict__ colw)
{
    int e = blockIdx.x * 256 + threadIdx.x;
    if (e < N_EDGES) {
        int pos = atomicAdd(cursor + row[e], 1);
        colw[pos] = col[e] * 256;
    }
}

// ---------------- fused attention, head-major: zero per-edge shuffles ----------
// lane = (edge-slot es=lane>>3, head h=lane&7). Per 8-edge step each lane gathers
// 16B k + 16B v for (its edge, its head), lane-local 16-FMA dot, 1 exp, 16 o-FMAs.
// Cross-lane reduce (xor 8/16/32 over es) once per node. Scores ~N(0,0.33^2) ->
// exp() w/o max-subtraction safe; /z normalizes.
__global__ __launch_bounds__(256) void attn_kernel(
    const unsigned short* __restrict__ qh, const unsigned char* __restrict__ kv8,
    const int* __restrict__ colw, const int* __restrict__ offs,
    const int* __restrict__ deg, unsigned short* __restrict__ aob)
{
    const int node = blockIdx.x * 4 + (threadIdx.x >> 6);
    const int lane = threadIdx.x & 63;
    const int h = lane & 7;
    const int es = lane >> 3;
    const int start = offs[node];
    const int d = deg[node];

    float qv[16];
    {
        const uint4* qp = (const uint4*)(qh + (size_t)node * 128 + h * 16);
        uint4 a = qp[0], b = qp[1];
        unsigned uu[8] = {a.x, a.y, a.z, a.w, b.x, b.y, b.z, b.w};
#pragma unroll
        for (int i = 0; i < 8; ++i) {
            qv[2 * i]     = __uint_as_float(uu[i] << 16);
            qv[2 * i + 1] = __uint_as_float(uu[i] & 0xffff0000u);
        }
    }
    float z = 0.f;
    float o[16];
#pragma unroll
    for (int i = 0; i < 16; ++i) o[i] = 0.f;

    for (int base = 0; base < d; base += 64) {
        const int nrem = min(64, d - base);
        int cl = 0;
        if (lane < nrem) cl = colw[start + base + lane];
        for (int j = 0; j < nrem; j += 8) {
            const int idx = j + es;
            const int cs = __shfl(cl, idx, 64);
            const bool valid = idx < nrem;
            uint4 kw = *(const uint4*)(kv8 + cs + h * 16);
            uint4 vw = *(const uint4*)(kv8 + cs + 128 + h * 16);
            unsigned kk[4] = {kw.x, kw.y, kw.z, kw.w};
            unsigned vv[4] = {vw.x, vw.y, vw.z, vw.w};
            float p0 = 0.f, p1 = 0.f, p2 = 0.f, p3 = 0.f;
#pragma unroll
            for (int w = 0; w < 4; ++w) {
                p0 = fmaf(qv[4 * w + 0], __builtin_amdgcn_cvt_f32_fp8((int)kk[w], 0), p0);
                p1 = fmaf(qv[4 * w + 1], __builtin_amdgcn_cvt_f32_fp8((int)kk[w], 1), p1);
                p2 = fmaf(qv[4 * w + 2], __builtin_amdgcn_cvt_f32_fp8((int)kk[w], 2), p2);
                p3 = fmaf(qv[4 * w + 3], __builtin_amdgcn_cvt_f32_fp8((int)kk[w], 3), p3);
            }
            const float p = (p0 + p1) + (p2 + p3);
            const float e = valid ? __expf(p) : 0.f;
            z += e;
#pragma unroll
            for (int w = 0; w < 4; ++w) {
                o[4 * w + 0] = fmaf(e, __builtin_amdgcn_cvt_f32_fp8((int)vv[w], 0), o[4 * w + 0]);
                o[4 * w + 1] = fmaf(e, __builtin_amdgcn_cvt_f32_fp8((int)vv[w], 1), o[4 * w + 1]);
                o[4 * w + 2] = fmaf(e, __builtin_amdgcn_cvt_f32_fp8((int)vv[w], 2), o[4 * w + 2]);
                o[4 * w + 3] = fmaf(e, __builtin_amdgcn_cvt_f32_fp8((int)vv[w], 3), o[4 * w + 3]);
            }
        }
    }

#pragma unroll
    for (int m = 8; m < 64; m <<= 1) {
        z += __shfl_xor(z, m, 64);
#pragma unroll
        for (int i = 0; i < 16; ++i) o[i] += __shfl_xor(o[i], m, 64);
    }
    if (es == 0) {
        const float rz = (d > 0) ? 1.f / z : 0.f;
        short8 w0, w1;
#pragma unroll
        for (int i = 0; i < 8; ++i) w0[i] = (short)f2b(o[i] * rz);
#pragma unroll
        for (int i = 0; i < 8; ++i) w1[i] = (short)f2b(o[8 + i] * rz);
        *(short8*)(aob + (size_t)node * 128 + h * 16)     = w0;
        *(short8*)(aob + (size_t)node * 128 + h * 16 + 8) = w1;
    }
}

// ---------------- BN apply (+ optional exact GELU), float4 vectorized ----------------
template<typename TO, bool ACT>
__global__ void bn_kernel(const float* __restrict__ x, const float* __restrict__ st,
                          const float* __restrict__ g, const float* __restrict__ b,
                          TO* __restrict__ out)
{
    const int i = (blockIdx.x * 256 + threadIdx.x) * 4;
    const int c = i & (HID - 1);
    float4 xv = *(const float4*)(x + i);
    float v[4] = {xv.x, xv.y, xv.z, xv.w};
#pragma unroll
    for (int u = 0; u < 4; ++u) {
        const int cc = c + u;
        float mu  = st[cc] * (1.0f / N_NODES);
        float var = st[HID + cc] * (1.0f / N_NODES) - mu * mu;
        float val = (v[u] - mu) * rsqrtf(var + 1e-5f) * g[cc] + b[cc];
        if constexpr (ACT) val = 0.5f * val * (1.0f + erff(val * 0.70710678118654752f));
        v[u] = val;
    }
    if constexpr (sizeof(TO) == 4) {
        *(float4*)((float*)out + i) = (float4){v[0], v[1], v[2], v[3]};
    } else {
        short4v w;
        w[0] = (short)f2b(v[0]); w[1] = (short)f2b(v[1]);
        w[2] = (short)f2b(v[2]); w[3] = (short)f2b(v[3]);
        *(short4v*)((unsigned short*)out + i) = w;
    }
}

extern "C" void kernel_launch(void* const* d_in, const int* in_sizes, int n_in,
                              void* d_out, int out_size, void* d_ws, size_t ws_size,
                              hipStream_t stream)
{
    const float* h   = (const float*)d_in[0];
    const int*   row = (const int*)d_in[1];
    const int*   col = (const int*)d_in[2];
    const float* Wq  = (const float*)d_in[3];
    const float* bq  = (const float*)d_in[4];
    const float* Wk  = (const float*)d_in[5];
    const float* bk  = (const float*)d_in[6];
    const float* Wv  = (const float*)d_in[7];
    const float* bv  = (const float*)d_in[8];
    const float* Wo  = (const float*)d_in[9];
    const float* bo  = (const float*)d_in[10];
    const float* W1  = (const float*)d_in[11];
    const float* bf1 = (const float*)d_in[12];
    const float* W2  = (const float*)d_in[13];
    const float* bf2 = (const float*)d_in[14];
    const float* g1  = (const float*)d_in[15];
    const float* b1  = (const float*)d_in[16];
    const float* g2  = (const float*)d_in[17];
    const float* b2  = (const float*)d_in[18];

    float* out = (float*)d_out;
    char*  ws  = (char*)d_ws;

    unsigned short* qh   = (unsigned short*)(ws + OFF_QB);
    unsigned char*  kv8  = (unsigned char*)(ws + OFF_KV8);
    unsigned short* aob  = (unsigned short*)(ws + OFF_AOB);
    unsigned short* xb   = (unsigned short*)(ws + OFF_XB);
    unsigned short* tb   = (unsigned short*)(ws + OFF_TB);
    unsigned short* hb   = (unsigned short*)(ws + OFF_HB);
    unsigned short* WTqkv= (unsigned short*)(ws + OFF_WQKV);
    unsigned short* WTo  = (unsigned short*)(ws + OFF_WTO);
    unsigned short* WT1  = (unsigned short*)(ws + OFF_WT1);
    unsigned short* WT2  = (unsigned short*)(ws + OFF_WT2);
    float* bqkv = (float*)(ws + OFF_BQKV);
    int*   deg  = (int*)(ws + OFF_DEG);
    int*   offs = (int*)(ws + OFF_OFFS);
    int*   cur  = (int*)(ws + OFF_CUR);
    int*   colw = (int*)(ws + OFF_COLW);
    int*   bsum = (int*)(ws + OFF_BSUM);
    float* st1  = (float*)(ws + OFF_ST);
    float* st2  = st1 + 256;

    dim3 blk(256);
    const int nScanBlocks = (N_NODES + 255) / 256;  // 157

    // wt_kernel also zeroes deg[] and st[] (replaces hipMemsetAsync fills)
    wt_kernel<<<dim3(512), blk, 0, stream>>>(Wq, Wk, Wv, Wo, W1, W2, bq, bk, bv,
                                             WTqkv, WTo, WT1, WT2, bqkv, deg, st1);
    h2b_kernel<<<dim3(2500), blk, 0, stream>>>(h, hb);

    // fused QKV projection: q -> qh (bf16 head-major), k/v -> kv8 (fp8 head-major)
    mm_kernel<unsigned short, void, 128, 384, false, false, true>
        <<<dim3(625, 3), blk, 0, stream>>>(hb, WTqkv, bqkv, nullptr, qh, kv8, nullptr);

    // CSR build
    count_kernel<<<dim3(N_EDGES / 256), blk, 0, stream>>>(row, deg);
    bsum_kernel<<<dim3(nScanBlocks), blk, 0, stream>>>(deg, bsum);
    scan2_kernel<<<dim3(nScanBlocks), blk, 0, stream>>>(deg, bsum, offs, cur);
    scatter_kernel<<<dim3(N_EDGES / 256), blk, 0, stream>>>(row, col, cur, colw);

    // fused attention
    attn_kernel<<<dim3(N_NODES / 4), blk, 0, stream>>>(qh, kv8, colw, offs, deg, aob);

    // output projection + residual(hb) -> x0 (f32, d_out), fused BN1 stats
    mm_kernel<float, unsigned short, 128, 128, false, true, false>
        <<<dim3(625, 1), blk, 0, stream>>>(aob, WTo, bo, hb, out, nullptr, st1);

    // BN1 + GELU -> x (bf16)
    bn_kernel<unsigned short, true>
        <<<dim3(N_NODES * HID / 1024), blk, 0, stream>>>(out, st1, g1, b1, xb);

    // FFN1: x @ W1 + b -> GELU -> t (bf16)
    mm_kernel<unsigned short, void, 128, 256, true, false, false>
        <<<dim3(625, 2), blk, 0, stream>>>(xb, WT1, bf1, nullptr, tb, nullptr, nullptr);

    // FFN2: t @ W2 + b + x -> y0 (f32, d_out), fused BN2 stats
    mm_kernel<float, unsigned short, 256, 128, false, true, false>
        <<<dim3(625, 1), blk, 0, stream>>>(tb, WT2, bf2, xb, out, nullptr, st2);

    // BN2 -> final output (in place on d_out)
    bn_kernel<float, false>
        <<<dim3(N_NODES * HID / 1024), blk, 0, stream>>>(out, st2, g2, b2, out);
}